// Round 2
// baseline (358.368 us; speedup 1.0000x reference)
//
#include <hip/hip_runtime.h>
#include <hip/hip_bf16.h>

// ---------- types ----------
typedef __bf16 bf16x8 __attribute__((ext_vector_type(8)));
typedef float  f32x4  __attribute__((ext_vector_type(4)));
typedef float  f32x4v __attribute__((ext_vector_type(4)));

#define LOG2E 1.44269504088896340736f

static __device__ __forceinline__ f32x4 mfma16(bf16x8 a, bf16x8 b, f32x4 c) {
    return __builtin_amdgcn_mfma_f32_16x16x32_bf16(a, b, c, 0, 0, 0);
}

static __device__ __forceinline__ void gload_lds16(const void* g, void* lds) {
    __builtin_amdgcn_global_load_lds(
        (const __attribute__((address_space(1))) void*)g,
        (__attribute__((address_space(3))) void*)lds, 16, 0, 0);
}

// ---------- weight transpose: WT[n][k] = W[k][n] * scale, bf16 ----------
// W: [Kdim][512] f32. grid*256 == Kdim*512 exactly.
__global__ void wtrans(const float* __restrict__ W, __bf16* __restrict__ WT,
                       int Kdim, float scale) {
    int idx = blockIdx.x * 256 + threadIdx.x;
    int k = idx >> 9, n = idx & 511;
    WT[(size_t)n * Kdim + k] = (__bf16)(W[idx] * scale);
}

// ---------- projection GEMM: C_bf16[M][512] = A_f32[M][Ktot] @ WT_bf16[512][Ktot]^T
// grid: (x = n-tile of 64, y = m-tile of 64). block 256 = 4 waves; wave w -> C rows 16w..16w+15.
__global__ __launch_bounds__(256) void proj_kernel(
    const float* __restrict__ A, const __bf16* __restrict__ WT,
    __bf16* __restrict__ Cout, int Ktot, int lda) {
    __shared__ uint4 smem[1024];              // 16 KB
    char* At = (char*)smem;                   // [64][128B], XOR-swizzled 16B blocks
    char* Wt = At + 8192;                     // [64][128B]

    const int tid = threadIdx.x, w = tid >> 6, lane = tid & 63;
    const int r = lane & 15, g = lane >> 4;
    const int m0 = blockIdx.y * 64, n0 = blockIdx.x * 64;

    f32x4 acc[4];
#pragma unroll
    for (int i = 0; i < 4; ++i) acc[i] = (f32x4){0.f, 0.f, 0.f, 0.f};

    for (int k0 = 0; k0 < Ktot; k0 += 64) {
        __syncthreads();
        // stage A (f32 -> bf16) and WT (bf16 copy); 512 16B blocks each
#pragma unroll
        for (int h = 0; h < 2; ++h) {
            int f = tid + h * 256;
            int row = f >> 3, blk = f & 7;
            int dsto = row * 128 + ((blk * 16) ^ ((row & 7) << 4));
            const float* ga = A + (size_t)(m0 + row) * lda + k0 + blk * 8;
            f32x4v x = *(const f32x4v*)ga;
            f32x4v y = *(const f32x4v*)(ga + 4);
            bf16x8 v;
            v[0] = (__bf16)x[0]; v[1] = (__bf16)x[1]; v[2] = (__bf16)x[2]; v[3] = (__bf16)x[3];
            v[4] = (__bf16)y[0]; v[5] = (__bf16)y[1]; v[6] = (__bf16)y[2]; v[7] = (__bf16)y[3];
            *(bf16x8*)(At + dsto) = v;
            *(bf16x8*)(Wt + dsto) =
                *(const bf16x8*)(WT + (size_t)(n0 + row) * Ktot + k0 + blk * 8);
        }
        __syncthreads();
#pragma unroll
        for (int c = 0; c < 2; ++c) {
            int arow = w * 16 + r;
            bf16x8 a = *(const bf16x8*)(At + arow * 128 + ((c * 64 + g * 16) ^ ((arow & 7) << 4)));
#pragma unroll
            for (int nt = 0; nt < 4; ++nt) {
                int brow = nt * 16 + r;
                bf16x8 b = *(const bf16x8*)(Wt + brow * 128 + ((c * 64 + g * 16) ^ ((brow & 7) << 4)));
                acc[nt] = mfma16(a, b, acc[nt]);
            }
        }
    }
#pragma unroll
    for (int nt = 0; nt < 4; ++nt)
#pragma unroll
        for (int j = 0; j < 4; ++j)
            Cout[(size_t)(m0 + w * 16 + g * 4 + j) * 512 + n0 + nt * 16 + r] = (__bf16)acc[nt][j];
}

// ---------- V^T GEMM: VT[b][s/32][h(512)][s%32] = (context[b] @ Wv)^T, bf16
// grid: (x = s-tile of 64 (16), y = h-tile of 64 (8), z = batch)
__global__ __launch_bounds__(256) void vt_gemm(
    const __bf16* __restrict__ WvT,   // [512 h][768 c]
    const float* __restrict__ ctx,    // [B][1024 s][768 c]
    __bf16* __restrict__ VT) {        // [B][32][512][32]
    __shared__ uint4 smem[1024];
    char* At = (char*)smem;            // WvT tile [64 h][128B]
    char* Bt = At + 8192;              // ctx tile [64 s][128B]

    const int tid = threadIdx.x, w = tid >> 6, lane = tid & 63;
    const int r = lane & 15, g = lane >> 4;
    const int m0 = blockIdx.y * 64;   // h
    const int n0 = blockIdx.x * 64;   // s
    const int b = blockIdx.z;
    const float* C0 = ctx + (size_t)b * 1024 * 768;

    f32x4 acc[4];
#pragma unroll
    for (int i = 0; i < 4; ++i) acc[i] = (f32x4){0.f, 0.f, 0.f, 0.f};

    for (int k0 = 0; k0 < 768; k0 += 64) {
        __syncthreads();
#pragma unroll
        for (int h = 0; h < 2; ++h) {
            int f = tid + h * 256;
            int row = f >> 3, blk = f & 7;
            int dsto = row * 128 + ((blk * 16) ^ ((row & 7) << 4));
            *(bf16x8*)(At + dsto) =
                *(const bf16x8*)(WvT + (size_t)(m0 + row) * 768 + k0 + blk * 8);
            const float* gb = C0 + (size_t)(n0 + row) * 768 + k0 + blk * 8;
            f32x4v x = *(const f32x4v*)gb;
            f32x4v y = *(const f32x4v*)(gb + 4);
            bf16x8 v;
            v[0] = (__bf16)x[0]; v[1] = (__bf16)x[1]; v[2] = (__bf16)x[2]; v[3] = (__bf16)x[3];
            v[4] = (__bf16)y[0]; v[5] = (__bf16)y[1]; v[6] = (__bf16)y[2]; v[7] = (__bf16)y[3];
            *(bf16x8*)(Bt + dsto) = v;
        }
        __syncthreads();
#pragma unroll
        for (int c = 0; c < 2; ++c) {
            int arow = w * 16 + r;
            bf16x8 a = *(const bf16x8*)(At + arow * 128 + ((c * 64 + g * 16) ^ ((arow & 7) << 4)));
#pragma unroll
            for (int nt = 0; nt < 4; ++nt) {
                int brow = nt * 16 + r;
                bf16x8 bb = *(const bf16x8*)(Bt + brow * 128 + ((c * 64 + g * 16) ^ ((brow & 7) << 4)));
                acc[nt] = mfma16(a, bb, acc[nt]);
            }
        }
    }
#pragma unroll
    for (int nt = 0; nt < 4; ++nt)
#pragma unroll
        for (int j = 0; j < 4; ++j) {
            int h = m0 + w * 16 + g * 4 + j;
            int s = n0 + nt * 16 + r;
            VT[((size_t)b * 32 + (s >> 5)) * 16384 + (size_t)h * 32 + (s & 31)] = (__bf16)acc[nt][j];
        }
}

// ---------- flash attention ----------
// grid (T/64, B), block 256 (4 waves); wave w owns q rows [qb*64+16w, +16).
// K LDS tile [32 s][1024B] swizzled ^((row&7)<<4); VT LDS tile [512 h][64B] swizzled ^((row&3)<<4).
__global__ __launch_bounds__(256, 2) void flash_kernel(
    const __bf16* __restrict__ Q,    // [B*4096][512] (pre-scaled by 1/sqrt(512))
    const __bf16* __restrict__ K,    // [B*1024][512]
    const __bf16* __restrict__ VT,   // [B][32][512][32]
    float* __restrict__ O) {         // [B*4096][512]
    __shared__ uint4 smem[4096];     // 64 KB
    char* Kt = (char*)smem;          // 32 KB
    char* Vt = Kt + 32768;           // 32 KB

    const int tid = threadIdx.x, w = tid >> 6, lane = tid & 63;
    const int r = lane & 15, g = lane >> 4;
    const int b = blockIdx.y, qb = blockIdx.x;

    const __bf16* Qrow = Q + ((size_t)(b * 4096 + qb * 64 + w * 16 + r)) * 512;
    bf16x8 q[16];
#pragma unroll
    for (int c = 0; c < 16; ++c) q[c] = *(const bf16x8*)(Qrow + c * 32 + g * 8);

    f32x4 acc[32];
#pragma unroll
    for (int i = 0; i < 32; ++i) acc[i] = (f32x4){0.f, 0.f, 0.f, 0.f};

    float mrun = -__builtin_inff(), lrun = 0.f;

    const size_t kbase = (size_t)b * 1024 * 512;
    const size_t vtbase = (size_t)b * 32 * 16384;

#pragma unroll 1
    for (int s0 = 0; s0 < 1024; s0 += 32) {
        __syncthreads();
        // stage K rows [w*8, w*8+8): one global_load_lds per row (1KB), pre-swizzled source
#pragma unroll
        for (int e = 0; e < 8; ++e) {
            int row = w * 8 + e;
            const char* gs = (const char*)(K + kbase + (size_t)(s0 + row) * 512) +
                             ((lane * 16) ^ ((row & 7) << 4));
            gload_lds16(gs, Kt + row * 1024);
        }
        // stage VT tile: 32 x 1KB chunks, chunk c covers rows [16c,16c+16)
        const char* vtile = (const char*)(VT + vtbase + (size_t)(s0 >> 5) * 16384);
#pragma unroll
        for (int e = 0; e < 8; ++e) {
            int c = w * 8 + e;
            int vrow = c * 16 + (lane >> 2);
            int bir = ((lane & 3) * 16) ^ ((vrow & 3) << 4);
            gload_lds16(vtile + vrow * 64 + bir, Vt + c * 1024);
        }
        __syncthreads();

        // swapped QK^T: ST[s][q] = mfma(Kfrag, Qfrag)
        f32x4 sc0 = (f32x4){0.f, 0.f, 0.f, 0.f};
        f32x4 sc1 = (f32x4){0.f, 0.f, 0.f, 0.f};
        const int sw = (r & 7) << 4;   // (r+16)&7 == r&7
#pragma unroll
        for (int c = 0; c < 16; ++c) {
            int bir = (c * 64 + g * 16) ^ sw;
            bf16x8 k0 = *(const bf16x8*)(Kt + r * 1024 + bir);
            bf16x8 k1 = *(const bf16x8*)(Kt + (r + 16) * 1024 + bir);
            sc0 = mfma16(k0, q[c], sc0);
            sc1 = mfma16(k1, q[c], sc1);
        }

        // online softmax for q = lane&15 (s values: sc0 -> 4g+j, sc1 -> 16+4g+j)
        float mt = fmaxf(fmaxf(fmaxf(sc0[0], sc0[1]), fmaxf(sc0[2], sc0[3])),
                         fmaxf(fmaxf(sc1[0], sc1[1]), fmaxf(sc1[2], sc1[3])));
        mt = fmaxf(mt, __shfl_xor(mt, 16, 64));
        mt = fmaxf(mt, __shfl_xor(mt, 32, 64));
        float mnew = fmaxf(mrun, mt);
        float corr = exp2f((mrun - mnew) * LOG2E);
        float p0[4], p1[4], ps = 0.f;
#pragma unroll
        for (int j = 0; j < 4; ++j) {
            p0[j] = exp2f((sc0[j] - mnew) * LOG2E);
            p1[j] = exp2f((sc1[j] - mnew) * LOG2E);
            ps += p0[j] + p1[j];
        }
        ps += __shfl_xor(ps, 16, 64);
        ps += __shfl_xor(ps, 32, 64);
        lrun = lrun * corr + ps;
        mrun = mnew;

        // CRITICAL: acc rows live in C/D layout (q = 4g+j), but corr was computed
        // for q = r (A-operand layout). Fetch the right factor per acc row.
        float corr4[4];
#pragma unroll
        for (int j = 0; j < 4; ++j) corr4[j] = __shfl(corr, g * 4 + j, 64);

        union { bf16x8 v; __bf16 e[8]; } pa;
#pragma unroll
        for (int j = 0; j < 4; ++j) { pa.e[j] = (__bf16)p0[j]; pa.e[4 + j] = (__bf16)p1[j]; }

        // PV: slot i<4 -> s'=4g+i, i>=4 -> s'=16+4g+(i-4); matching V^T b64 reads
#pragma unroll
        for (int ht = 0; ht < 32; ++ht) {
            int vrow = ht * 16 + r;
            int vsw = (vrow & 3) << 4;
            union { bf16x8 v; unsigned long long u[2]; } bv;
            bv.u[0] = *(const unsigned long long*)(Vt + vrow * 64 + ((g * 8) ^ vsw));
            bv.u[1] = *(const unsigned long long*)(Vt + vrow * 64 + ((32 + g * 8) ^ vsw));
            f32x4 a = acc[ht];
            a[0] *= corr4[0]; a[1] *= corr4[1]; a[2] *= corr4[2]; a[3] *= corr4[3];
            acc[ht] = mfma16(pa.v, bv.v, a);
        }
    }

    float rl[4];
#pragma unroll
    for (int j = 0; j < 4; ++j) rl[j] = 1.0f / __shfl(lrun, g * 4 + j, 64);

    float* Orow = O + ((size_t)(b * 4096 + qb * 64 + w * 16)) * 512;
#pragma unroll
    for (int ht = 0; ht < 32; ++ht)
#pragma unroll
        for (int j = 0; j < 4; ++j)
            Orow[(size_t)(g * 4 + j) * 512 + ht * 16 + r] = acc[ht][j] * rl[j];
}

// ---------- host ----------
extern "C" void kernel_launch(void* const* d_in, const int* in_sizes, int n_in,
                              void* d_out, int out_size, void* d_ws, size_t ws_size,
                              hipStream_t stream) {
    const float* tokens  = (const float*)d_in[0];
    const float* context = (const float*)d_in[1];
    const float* Wq      = (const float*)d_in[2];
    const float* Wk      = (const float*)d_in[3];
    const float* Wv      = (const float*)d_in[4];
    float* out = (float*)d_out;

    __bf16* WqT = (__bf16*)d_ws;                        // 512*512
    __bf16* WkT = WqT + (size_t)512 * 512;              // 512*768
    __bf16* WvT = WkT + (size_t)512 * 768;              // 512*768
    __bf16* Qws = WvT + (size_t)512 * 768;              // 32768*512
    __bf16* Kws = Qws + (size_t)32768 * 512;            // 8192*512
    __bf16* VTw = Kws + (size_t)8192 * 512;             // 8*32*512*32

    wtrans<<<1024, 256, 0, stream>>>(Wq, WqT, 512, 0.044194173824159216f); // 1/sqrt(512)
    wtrans<<<1536, 256, 0, stream>>>(Wk, WkT, 768, 1.0f);
    wtrans<<<1536, 256, 0, stream>>>(Wv, WvT, 768, 1.0f);

    proj_kernel<<<dim3(8, 512), 256, 0, stream>>>(tokens,  WqT, Qws, 512, 512);
    proj_kernel<<<dim3(8, 128), 256, 0, stream>>>(context, WkT, Kws, 768, 768);
    vt_gemm<<<dim3(16, 8, 8), 256, 0, stream>>>(WvT, context, VTw);

    flash_kernel<<<dim3(64, 8), 256, 0, stream>>>(Qws, Kws, VTw, out);
}

// Round 3
// 212.976 us; speedup vs baseline: 1.6827x; 1.6827x over previous
//
#include <hip/hip_runtime.h>
#include <hip/hip_bf16.h>

// ---------- types ----------
typedef __bf16 bf16x8 __attribute__((ext_vector_type(8)));
typedef float  f32x4  __attribute__((ext_vector_type(4)));
typedef float  f32x4v __attribute__((ext_vector_type(4)));

#define LOG2E 1.44269504088896340736f

static __device__ __forceinline__ f32x4 mfma16(bf16x8 a, bf16x8 b, f32x4 c) {
    return __builtin_amdgcn_mfma_f32_16x16x32_bf16(a, b, c, 0, 0, 0);
}

static __device__ __forceinline__ void gload_lds16(const void* g, void* lds) {
    __builtin_amdgcn_global_load_lds(
        (const __attribute__((address_space(1))) void*)g,
        (__attribute__((address_space(3))) void*)lds, 16, 0, 0);
}

// ---------- f32 -> bf16 elementwise (8 elems/thread, exact grid) ----------
__global__ void cvt_bf16(const float* __restrict__ in, __bf16* __restrict__ out) {
    size_t i = ((size_t)blockIdx.x * 256 + threadIdx.x) * 8;
    f32x4v x = *(const f32x4v*)(in + i);
    f32x4v y = *(const f32x4v*)(in + i + 4);
    bf16x8 v;
    v[0] = (__bf16)x[0]; v[1] = (__bf16)x[1]; v[2] = (__bf16)x[2]; v[3] = (__bf16)x[3];
    v[4] = (__bf16)y[0]; v[5] = (__bf16)y[1]; v[6] = (__bf16)y[2]; v[7] = (__bf16)y[3];
    *(bf16x8*)(out + i) = v;
}

// ---------- weight transpose: WT[n][k] = W[k][n] * scale, bf16 ----------
__global__ void wtrans(const float* __restrict__ W, __bf16* __restrict__ WT,
                       int Kdim, float scale) {
    int idx = blockIdx.x * 256 + threadIdx.x;
    int k = idx >> 9, n = idx & 511;
    WT[(size_t)n * Kdim + k] = (__bf16)(W[idx] * scale);
}

// ---------- 128x128-tile GEMM, BK=64, double-buffered gload_lds ----------
// C[m][n] = sum_k A[m][k] * Bw[n][k]; A,Bw bf16 row-major [*][Ktot].
// MODE 0: C bf16 [M][512] row-major.  MODE 1 (V^T): C = VT[z][s/32][h][perm(s%32)],
//   m-dim = h, n-dim = s (per batch z), perm interleaves the two 16-s halves.
// block 256 = 4 waves (2x2); wave (wr,wc) computes 64x64; LDS 64 KB (2 buf x (16+16) KB).
template<int MODE>
__global__ __launch_bounds__(256, 2) void gemm128(
    const __bf16* __restrict__ A, const __bf16* __restrict__ Bw,
    __bf16* __restrict__ C, int Ktot, size_t sAz, size_t sBz) {
    __shared__ char smem[65536];
    const int tid = threadIdx.x, w = tid >> 6, lane = tid & 63;
    const int r = lane & 15, g = lane >> 4;
    const int wr = w >> 1, wc = w & 1;
    const int m0 = blockIdx.y * 128, n0 = blockIdx.x * 128;
    const int z = blockIdx.z;
    const __bf16* Az = A + sAz * z;
    const __bf16* Bz = Bw + sBz * z;

    f32x4 acc[4][4];
#pragma unroll
    for (int i = 0; i < 4; ++i)
#pragma unroll
        for (int j = 0; j < 4; ++j) acc[i][j] = (f32x4){0.f, 0.f, 0.f, 0.f};

    const int nsteps = Ktot >> 6;

    auto STAGE = [&](int t) {
        char* bufA = smem + (t & 1) * 32768;
        char* bufB = bufA + 16384;
        int k0 = t * 64;
#pragma unroll
        for (int e = 0; e < 4; ++e) {
            int rows8 = w * 32 + e * 8;
            int row = rows8 + (lane >> 3);
            int so = ((lane & 7) ^ (row & 7)) << 4;
            gload_lds16((const char*)(Az + (size_t)(m0 + row) * Ktot + k0) + so,
                        bufA + rows8 * 128);
            gload_lds16((const char*)(Bz + (size_t)(n0 + row) * Ktot + k0) + so,
                        bufB + rows8 * 128);
        }
    };

    STAGE(0);
#pragma unroll 1
    for (int t = 0; t < nsteps; ++t) {
        __builtin_amdgcn_s_barrier();                  // buf[(t+1)&1] readers done
        if (t + 1 < nsteps) {
            STAGE(t + 1);
            asm volatile("s_waitcnt vmcnt(8)" ::: "memory");   // tile-t loads landed
        } else {
            asm volatile("s_waitcnt vmcnt(0)" ::: "memory");
        }
        __builtin_amdgcn_s_barrier();                  // everyone's tile-t landed
        __builtin_amdgcn_sched_barrier(0);
        char* bufA = smem + (t & 1) * 32768;
        char* bufB = bufA + 16384;
#pragma unroll
        for (int c = 0; c < 2; ++c) {
            bf16x8 a[4], bb[4];
#pragma unroll
            for (int mt = 0; mt < 4; ++mt) {
                int ar = wr * 64 + mt * 16 + r;
                a[mt] = *(const bf16x8*)(bufA + ar * 128 + (((c * 4 + g) ^ (ar & 7)) << 4));
            }
#pragma unroll
            for (int nt = 0; nt < 4; ++nt) {
                int br = wc * 64 + nt * 16 + r;
                bb[nt] = *(const bf16x8*)(bufB + br * 128 + (((c * 4 + g) ^ (br & 7)) << 4));
            }
            __builtin_amdgcn_s_setprio(1);
#pragma unroll
            for (int mt = 0; mt < 4; ++mt)
#pragma unroll
                for (int nt = 0; nt < 4; ++nt)
                    acc[mt][nt] = mfma16(a[mt], bb[nt], acc[mt][nt]);
            __builtin_amdgcn_s_setprio(0);
        }
    }

#pragma unroll
    for (int mt = 0; mt < 4; ++mt)
#pragma unroll
        for (int nt = 0; nt < 4; ++nt)
#pragma unroll
            for (int j = 0; j < 4; ++j) {
                int m = m0 + wr * 64 + mt * 16 + g * 4 + j;
                int n = n0 + wc * 64 + nt * 16 + r;
                if (MODE == 0) {
                    C[(size_t)m * 512 + n] = (__bf16)acc[mt][nt][j];
                } else {
                    int l = n & 31;
                    int perm = ((l >> 2) & 3) * 8 + ((l >> 4) & 1) * 4 + (l & 3);
                    C[(((size_t)z * 32 + (n >> 5)) * 512 + m) * 32 + perm] =
                        (__bf16)acc[mt][nt][j];
                }
            }
}

// ---------- flash attention ----------
// grid (T/128, B), block 512 = 8 waves; wave w owns q rows [qb*128+16w, +16).
// LDS 128 KB: 2 bufs x { K tile [32 s][1024B] swizzled ^((row&7)<<4) |
//                        VT tile [512 h][64B] interleaved-s, blk ^ ((row>>1)&3) }.
// Double-buffered: stage(t+1) in flight across compute(t) via counted vmcnt.
__global__ __launch_bounds__(512, 2) void flash_kernel(
    const __bf16* __restrict__ Q,    // [B*4096][512] (pre-scaled by 1/sqrt(512))
    const __bf16* __restrict__ Kg,   // [B*1024][512]
    const __bf16* __restrict__ VT,   // [B][32][512 h][32 s interleaved]
    float* __restrict__ O) {         // [B*4096][512]
    __shared__ char smem[131072];

    const int tid = threadIdx.x, w = tid >> 6, lane = tid & 63;
    const int r = lane & 15, g = lane >> 4;
    const int b = blockIdx.y, qb = blockIdx.x;

    const __bf16* Qrow = Q + ((size_t)b * 4096 + qb * 128 + w * 16 + r) * 512;
    bf16x8 q[16];
#pragma unroll
    for (int c = 0; c < 16; ++c) q[c] = *(const bf16x8*)(Qrow + c * 32 + g * 8);

    f32x4 acc[32];
#pragma unroll
    for (int i = 0; i < 32; ++i) acc[i] = (f32x4){0.f, 0.f, 0.f, 0.f};

    float mrun = -__builtin_inff(), lrun = 0.f;

    const size_t kbase = (size_t)b * 1024 * 512;

    auto STAGE = [&](int it) {
        char* bufc = smem + (it & 1) * 65536;
        const char* ksrc = (const char*)(Kg + kbase + (size_t)(it * 32) * 512);
#pragma unroll
        for (int e = 0; e < 4; ++e) {
            int row = w * 4 + e;
            gload_lds16(ksrc + row * 1024 + ((lane * 16) ^ ((row & 7) << 4)),
                        bufc + row * 1024);
        }
        const char* vtile = (const char*)(VT + ((size_t)b * 32 + it) * 16384);
#pragma unroll
        for (int e = 0; e < 4; ++e) {
            int c2 = w * 4 + e;
            gload_lds16(vtile + (c2 * 16 + (lane >> 2)) * 64 +
                            (((lane & 3) ^ ((lane >> 3) & 3)) << 4),
                        bufc + 32768 + c2 * 1024);
        }
    };

    STAGE(0);
#pragma unroll 1
    for (int it = 0; it < 32; ++it) {
        __builtin_amdgcn_s_barrier();                  // buf[(it+1)&1] readers done
        if (it < 31) {
            STAGE(it + 1);
            asm volatile("s_waitcnt vmcnt(8)" ::: "memory");  // tile-it loads landed
        } else {
            asm volatile("s_waitcnt vmcnt(0)" ::: "memory");
        }
        __builtin_amdgcn_s_barrier();                  // all waves' tile-it landed
        __builtin_amdgcn_sched_barrier(0);

        char* Kt = smem + (it & 1) * 65536;
        char* Vt = Kt + 32768;

        // swapped QK^T: S^T[s][q] = mfma(Kfrag, Qfrag)
        f32x4 sc0 = (f32x4){0.f, 0.f, 0.f, 0.f};
        f32x4 sc1 = (f32x4){0.f, 0.f, 0.f, 0.f};
        const int sw = (r & 7) << 4;   // (r+16)&7 == r&7
        __builtin_amdgcn_s_setprio(1);
#pragma unroll
        for (int c = 0; c < 16; ++c) {
            int bir = (c * 64 + g * 16) ^ sw;
            bf16x8 k0 = *(const bf16x8*)(Kt + r * 1024 + bir);
            bf16x8 k1 = *(const bf16x8*)(Kt + (r + 16) * 1024 + bir);
            sc0 = mfma16(k0, q[c], sc0);
            sc1 = mfma16(k1, q[c], sc1);
        }
        __builtin_amdgcn_s_setprio(0);

        // online softmax for q = r (A-layout); s-slots: sc0 -> 4g+j, sc1 -> 16+4g+j
        float mt = fmaxf(fmaxf(fmaxf(sc0[0], sc0[1]), fmaxf(sc0[2], sc0[3])),
                         fmaxf(fmaxf(sc1[0], sc1[1]), fmaxf(sc1[2], sc1[3])));
        mt = fmaxf(mt, __shfl_xor(mt, 16, 64));
        mt = fmaxf(mt, __shfl_xor(mt, 32, 64));
        float mnew = fmaxf(mrun, mt);
        float corr = exp2f((mrun - mnew) * LOG2E);
        float p0[4], p1[4], ps = 0.f;
#pragma unroll
        for (int j = 0; j < 4; ++j) {
            p0[j] = exp2f((sc0[j] - mnew) * LOG2E);
            p1[j] = exp2f((sc1[j] - mnew) * LOG2E);
            ps += p0[j] + p1[j];
        }
        ps += __shfl_xor(ps, 16, 64);
        ps += __shfl_xor(ps, 32, 64);
        lrun = lrun * corr + ps;
        mrun = mnew;

        // acc rows live in C/D layout (q = 4g+j); corr is per q = r. Redistribute.
        float corr4[4];
#pragma unroll
        for (int j = 0; j < 4; ++j) corr4[j] = __shfl(corr, g * 4 + j, 64);

        union { bf16x8 v; __bf16 e[8]; } pa;
#pragma unroll
        for (int j = 0; j < 4; ++j) { pa.e[j] = (__bf16)p0[j]; pa.e[4 + j] = (__bf16)p1[j]; }

        // PV: one b128 per h-row; interleaved row gives slots [0..3]=G0, [4..7]=G1
        __builtin_amdgcn_s_setprio(1);
#pragma unroll
        for (int ht = 0; ht < 32; ++ht) {
            int vrow = ht * 16 + r;
            bf16x8 bv = *(const bf16x8*)(Vt + vrow * 64 + ((g ^ ((r >> 1) & 3)) << 4));
            f32x4 a = acc[ht];
            a[0] *= corr4[0]; a[1] *= corr4[1]; a[2] *= corr4[2]; a[3] *= corr4[3];
            acc[ht] = mfma16(pa.v, bv, a);
        }
        __builtin_amdgcn_s_setprio(0);
    }

    float rl[4];
#pragma unroll
    for (int j = 0; j < 4; ++j) rl[j] = 1.0f / __shfl(lrun, g * 4 + j, 64);

    float* Orow = O + ((size_t)b * 4096 + qb * 128 + w * 16) * 512;
#pragma unroll
    for (int ht = 0; ht < 32; ++ht)
#pragma unroll
        for (int j = 0; j < 4; ++j)
            Orow[(size_t)(g * 4 + j) * 512 + ht * 16 + r] = acc[ht][j] * rl[j];
}

// ---------- host ----------
extern "C" void kernel_launch(void* const* d_in, const int* in_sizes, int n_in,
                              void* d_out, int out_size, void* d_ws, size_t ws_size,
                              hipStream_t stream) {
    const float* tokens  = (const float*)d_in[0];
    const float* context = (const float*)d_in[1];
    const float* Wq      = (const float*)d_in[2];
    const float* Wk      = (const float*)d_in[3];
    const float* Wv      = (const float*)d_in[4];
    float* out = (float*)d_out;

    __bf16* tokb = (__bf16*)d_ws;                       // 8*4096*512
    __bf16* ctxb = tokb + (size_t)16777216;             // 8*1024*768
    __bf16* WqT  = ctxb + (size_t)6291456;              // 512*512
    __bf16* WkT  = WqT  + (size_t)262144;               // 512*768
    __bf16* WvT  = WkT  + (size_t)393216;               // 512*768
    __bf16* Qws  = WvT  + (size_t)393216;               // 32768*512
    __bf16* Kws  = Qws  + (size_t)16777216;             // 8192*512
    __bf16* VTw  = Kws  + (size_t)4194304;              // 8*32*512*32

    cvt_bf16<<<8192, 256, 0, stream>>>(tokens, tokb);
    cvt_bf16<<<3072, 256, 0, stream>>>(context, ctxb);
    wtrans<<<1024, 256, 0, stream>>>(Wq, WqT, 512, 0.044194173824159216f); // 1/sqrt(512)
    wtrans<<<1536, 256, 0, stream>>>(Wk, WkT, 768, 1.0f);
    wtrans<<<1536, 256, 0, stream>>>(Wv, WvT, 768, 1.0f);

    gemm128<0><<<dim3(4, 256), 256, 0, stream>>>(tokb, WqT, Qws, 512, 0, 0);
    gemm128<0><<<dim3(4, 64),  256, 0, stream>>>(ctxb, WkT, Kws, 768, 0, 0);
    gemm128<1><<<dim3(8, 4, 8), 256, 0, stream>>>(WvT, ctxb, VTw, 768, 0, (size_t)1024 * 768);

    flash_kernel<<<dim3(32, 8), 512, 0, stream>>>(Qws, Kws, VTw, out);
}